// Round 16
// baseline (141.808 us; speedup 1.0000x reference)
//
#include <hip/hip_runtime.h>
#include <hip/hip_bf16.h>
#include <math.h>

#define TSEQ 2048
#define CEMB 1024
#define NHEAD 16
#define HS 64

typedef __attribute__((ext_vector_type(8))) short bf16x8;
typedef __attribute__((ext_vector_type(4))) float f32x4;
typedef __attribute__((ext_vector_type(16))) float f32x16;
typedef unsigned int u32;
typedef unsigned long long u64;
typedef unsigned short u16;

__device__ __forceinline__ void gload16(const void* g, void* l) {
    __builtin_amdgcn_global_load_lds(
        (const __attribute__((address_space(1))) unsigned int*)g,
        (__attribute__((address_space(3))) unsigned int*)l, 16, 0, 0);
}

__device__ __forceinline__ u32 pk2(float a, float b) {
    union { u32 u; __hip_bfloat16 h[2]; } t;
    t.h[0] = __float2bfloat16(a); t.h[1] = __float2bfloat16(b);
    return t.u;
}

__device__ __forceinline__ u16 bf16u(float a) {
    union { u16 u; __hip_bfloat16 h; } t;
    t.h = __float2bfloat16(a);
    return t.u;
}

// ---- 24-unit scheme (3 blocks/CU, proven R11): CU triple sums 34 rounds ----
__device__ const int UNIT_TBL[24] = {22,7,20,21,19,17,6,14,
                                     23,18,16,12,4,5,13,15,
                                     0,1,2,3,10,8,9,11};

// ---- 32-unit scheme (4 blocks/CU): qbb0-3 unsplit, 4-11 2-way, 12-15 3-way.
// T32: upos->unit; CU c gets upos {j,j+8,j+16,j+24}, each quadruple sums 34 rounds.
__device__ const int T32[32]   = {18,16,30,15,26,28,13,23,
                                  19,17,31,25,27,29,21,24,
                                  2,14,8,12,3,10,22,11,
                                  1,0,4,5,6,7,9,20};
__device__ const int U_QBB[32] = {0,1,2,3, 4,4,5,5,6,6,7,7,8,8,9,9,10,10,11,11,
                                  12,12,12,13,13,13,14,14,14,15,15,15};
__device__ const int U_KT0[32] = {0,0,0,0, 0,5,0,6,0,7,0,8,0,9,0,10,0,11,0,12,
                                  0,8,17,0,9,18,0,10,20,0,10,21};
__device__ const int U_KTN[32] = {2,4,6,8, 5,10,6,12,7,14,8,16,9,18,10,20,11,22,12,24,
                                  8,17,26,9,18,28,10,20,30,10,21,32};
__device__ const int U_P[32]   = {-1,-1,-1,-1, 0,1,2,3,4,5,6,7,8,9,10,11,12,13,14,15,
                                  16,17,18,19,20,21,22,23,24,25,26,27};

// ---------------- fused prep: x->bf16, RoPE table, both weight transposes ---
// Reference quirk: _apply_rope uses cache[:d1] where d1 = n_head after the
// transpose, so the rotation angle is head_index * theta_j (constant over t).
__device__ __forceinline__ void transpose_tile(const float* __restrict__ src,
                                               __hip_bfloat16* __restrict__ dst,
                                               int K, int N, int n0, int k0) {
    __shared__ float tile[32][33];
    int tx = threadIdx.x & 31, ty = threadIdx.x >> 5;
#pragma unroll
    for (int i = 0; i < 32; i += 8)
        tile[ty + i][tx] = src[(size_t)(k0 + ty + i) * N + n0 + tx];
    __syncthreads();
#pragma unroll
    for (int i = 0; i < 32; i += 8)
        dst[(size_t)(n0 + ty + i) * K + k0 + tx] = __float2bfloat16(tile[tx][ty + i]);
}

__global__ __launch_bounds__(256) void prep_k(
    const float* __restrict__ x, __hip_bfloat16* __restrict__ Xb,
    float* __restrict__ tbl,
    const float* __restrict__ w_attn, __hip_bfloat16* __restrict__ Wta,
    const float* __restrict__ w_proj, __hip_bfloat16* __restrict__ Wpt)
{
    const int id = blockIdx.x;
    if (id < 2048) {
        int i = (id * 256 + threadIdx.x) * 8;
        float4 a = *(const float4*)(x + i);
        float4 b = *(const float4*)(x + i + 4);
        union { bf16x8 v; __hip_bfloat16 h[8]; } pk;
        pk.h[0] = __float2bfloat16(a.x); pk.h[1] = __float2bfloat16(a.y);
        pk.h[2] = __float2bfloat16(a.z); pk.h[3] = __float2bfloat16(a.w);
        pk.h[4] = __float2bfloat16(b.x); pk.h[5] = __float2bfloat16(b.y);
        pk.h[6] = __float2bfloat16(b.z); pk.h[7] = __float2bfloat16(b.w);
        *(bf16x8*)(Xb + i) = pk.v;
    } else if (id == 2048) {
#pragma unroll
        for (int it = 0; it < 2; ++it) {
            int idx = threadIdx.x + 256 * it;
            int h = idx >> 5, j = idx & 31;
            double theta = pow(10000.0, -2.0 * (double)j / 1024.0);
            double ang = (double)h * theta;
            tbl[2 * idx + 0] = (float)cos(ang);
            tbl[2 * idx + 1] = (float)sin(ang);
        }
    } else if (id < 2049 + 3072) {
        int t = id - 2049;
        transpose_tile(w_attn, Wta, CEMB, 3 * CEMB, (t % 96) * 32, (t / 96) * 32);
    } else {
        int t = id - (2049 + 3072);
        transpose_tile(w_proj, Wpt, CEMB, CEMB, (t & 31) * 32, (t >> 5) * 32);
    }
}

// ---------------- QKV GEMM, bf16 MFMA, RoPE epilogue ----------------
__global__ __launch_bounds__(256) void qkv_mfma_k(
    const __hip_bfloat16* __restrict__ Xb, const __hip_bfloat16* __restrict__ Wt,
    const float* __restrict__ bias, const float* __restrict__ tbl,
    __hip_bfloat16* __restrict__ Qb, __hip_bfloat16* __restrict__ Kb,
    __hip_bfloat16* __restrict__ Vtb)
{
    __shared__ __hip_bfloat16 SM[4][128 * 32];   // A dbuf = SM[0..1], B dbuf = SM[2..3]
    const int tid = threadIdx.x;
    const int lane = tid & 63, w = tid >> 6;
    const int lr = lane & 15, lg = lane >> 4;
    const int wm = w >> 1, wn = w & 1;
    const int n0 = blockIdx.x * 128;
    const int m0 = blockIdx.y * 128;
    const __hip_bfloat16* gA = Xb + (size_t)(m0 + (tid >> 2)) * CEMB + (tid & 3) * 8;
    const __hip_bfloat16* gB = Wt + (size_t)(n0 + (tid >> 2)) * CEMB + (tid & 3) * 8;
#define QSTAGE(buf, kk) do { \
        gload16(gA + (kk), &SM[buf][tid * 8]); \
        gload16(gA + 64 * CEMB + (kk), &SM[buf][2048 + tid * 8]); \
        gload16(gB + (kk), &SM[2 + (buf)][tid * 8]); \
        gload16(gB + 64 * CEMB + (kk), &SM[2 + (buf)][2048 + tid * 8]); } while (0)
    f32x4 acc[4][4] = {};
    QSTAGE(0, 0);
    __syncthreads();
    for (int k0 = 0; k0 < CEMB; k0 += 32) {
        const int cur = (k0 >> 5) & 1;
        if (k0 + 32 < CEMB) QSTAGE(cur ^ 1, k0 + 32);
        bf16x8 af[4], bfr[4];
#pragma unroll
        for (int mi = 0; mi < 4; ++mi)
            af[mi] = *(const bf16x8*)&SM[cur][(wm * 64 + mi * 16 + lr) * 32 + lg * 8];
#pragma unroll
        for (int ni = 0; ni < 4; ++ni)
            bfr[ni] = *(const bf16x8*)&SM[2 + cur][(wn * 64 + ni * 16 + lr) * 32 + lg * 8];
#pragma unroll
        for (int mi = 0; mi < 4; ++mi)
#pragma unroll
            for (int ni = 0; ni < 4; ++ni)
                acc[mi][ni] = __builtin_amdgcn_mfma_f32_16x16x32_bf16(af[mi], bfr[ni], acc[mi][ni], 0, 0, 0);
        __syncthreads();
    }
    const int sec = (n0 >> 10);
    const int bb = m0 >> 11;
    const int t0v = m0 & 2047;
    const int h0 = (n0 & 1023) >> 6;
    if (sec == 2) {
        char* T = (char*)SM;   // [128 n][128 m] bf16, row stride 256B
#pragma unroll
        for (int mi = 0; mi < 4; ++mi) {
#pragma unroll
            for (int ni = 0; ni < 4; ++ni) {
                const int nl = wn * 64 + ni * 16 + lr;
                const float bv = bias[n0 + nl];
                const int mb = wm * 64 + mi * 16 + lg * 4;
                union { u64 u; __hip_bfloat16 hh[4]; } pk;
#pragma unroll
                for (int r = 0; r < 4; ++r) pk.hh[r] = __float2bfloat16(acc[mi][ni][r] + bv);
                *(u64*)(T + nl * 256 + ((mb * 2) ^ ((nl & 7) << 4))) = pk.u;
            }
        }
        __syncthreads();
#pragma unroll
        for (int i = 0; i < 8; ++i) {
            int cid = tid + 256 * i;
            int n = cid >> 4, mc = cid & 15;
            bf16x8 v = *(const bf16x8*)(T + n * 256 + ((mc * 16) ^ ((n & 7) << 4)));
            *(bf16x8*)&Vtb[(((size_t)bb * NHEAD + h0 + (n >> 6)) * HS + (n & 63)) * TSEQ + t0v + mc * 8] = v;
        }
    } else {
        char* T = (char*)SM;   // [128 m][128 n] bf16, row stride 256B
        const float sc = (sec == 0) ? 0.18033688011112042f : 1.0f;  // 1/8*log2e for Q
        __hip_bfloat16* dst = (sec == 0) ? Qb : Kb;
#pragma unroll
        for (int mi = 0; mi < 4; ++mi) {
#pragma unroll
            for (int ni = 0; ni < 4; ++ni) {
                const int nl = wn * 64 + ni * 16 + lr;
                const int c63 = (n0 + nl) & 63;
                const int h = h0 + (nl >> 6);
                const int j = c63 >> 1;
                const float cth = tbl[(h * 32 + j) * 2 + 0];
                const float sth = tbl[(h * 32 + j) * 2 + 1];
                const float bv = bias[n0 + nl];
                const int mb = wm * 64 + mi * 16 + lg * 4;
#pragma unroll
                for (int r = 0; r < 4; ++r) {
                    float val = acc[mi][ni][r] + bv;
                    float prt = __shfl_xor(val, 1);
                    float rot = (lr & 1) ? (val * cth + prt * sth) : (val * cth - prt * sth);
                    const int row = mb + r;
                    *(u16*)(T + row * 256 + ((nl * 2) ^ ((row & 7) << 4))) = bf16u(rot * sc);
                }
            }
        }
        __syncthreads();
#pragma unroll
        for (int i = 0; i < 8; ++i) {
            int cid = tid + 256 * i;
            int row = cid >> 4, nc = cid & 15;
            bf16x8 v = *(const bf16x8*)(T + row * 256 + ((nc * 16) ^ ((row & 7) << 4)));
            int col = nc * 8;
            *(bf16x8*)&dst[(((size_t)bb * NHEAD + h0 + (col >> 6)) * TSEQ + t0v + row) * HS + (col & 63)] = v;
        }
    }
#undef QSTAGE
}

// ---------------- split-K flash attention (R11-proven body, 2 schemes) -----
// DEEP=0: 768 blocks, 24 units/bh (3/CU, chain<=16). DEEP=1: 1024 blocks,
// 32 units/bh (4/CU, chain<=12; qbb4-11 2-way, qbb12-15 3-way).
template <int DEEP>
__global__ __launch_bounds__(256) void attn_split_k(
    const __hip_bfloat16* __restrict__ Q, const __hip_bfloat16* __restrict__ K,
    const __hip_bfloat16* __restrict__ Vt, __hip_bfloat16* __restrict__ Y,
    float* __restrict__ Op, float* __restrict__ Mp, float* __restrict__ Lp)
{
    __shared__ __hip_bfloat16 KsBuf[2][64 * 64];   // [kv][hs], swizzled
    __shared__ __hip_bfloat16 VsBuf[2][64 * 64];   // [hs][kv], swizzled
    const int tid = threadIdx.x;                   // 0..255
    const int w = tid >> 6;
    const int lane = tid & 63;
    const int l31 = lane & 31;
    const int hi = lane >> 5;
    const int id = blockIdx.x;
    const int bh = id & 31;
    int qbb, kt0, ktN, pslot;
    bool split;
    if (DEEP) {
        const int u = T32[id >> 5];
        qbb = U_QBB[u]; kt0 = U_KT0[u]; ktN = U_KTN[u]; pslot = U_P[u];
        split = (pslot >= 0);
    } else {
        const int u = UNIT_TBL[id >> 5];
        if (u < 8) { qbb = u; kt0 = 0; ktN = 2 * u + 2; pslot = -1; split = false; }
        else {
            qbb = 8 + ((u - 8) >> 1); const int half = (u - 8) & 1;
            kt0 = half ? (qbb + 1) : 0;
            ktN = half ? (2 * qbb + 2) : (qbb + 1);
            pslot = (qbb - 8) * 2 + half; split = true;
        }
    }
    const size_t bho = (size_t)bh * TSEQ * HS;
    const int Qw = qbb * 128 + w * 32;             // global q base of this wave

    int srcK[2], srcV[2];
#pragma unroll
    for (int j = 0; j < 2; ++j) {
        int L = (tid + 256 * j) * 16;
        int row = L >> 7;
        int ce = ((L & 127) ^ (((row ^ (row >> 3)) & 7) << 4)) >> 1;
        srcK[j] = row * HS + ce;
        srcV[j] = row * TSEQ + ce;
    }
    const __hip_bfloat16* Kg = K + bho;
    const __hip_bfloat16* Vg = Vt + bho;
#define ASTAGE(buf, kt_) do { \
        const __hip_bfloat16* kg_ = Kg + (size_t)(kt_) * 64 * HS; \
        const __hip_bfloat16* vg_ = Vg + (size_t)(kt_) * 64; \
        char* kb_ = (char*)KsBuf[buf]; char* vb_ = (char*)VsBuf[buf]; \
        _Pragma("unroll") \
        for (int j = 0; j < 2; ++j) { \
            gload16(kg_ + srcK[j], kb_ + (tid + 256 * j) * 16); \
            gload16(vg_ + srcV[j], vb_ + (tid + 256 * j) * 16); } } while (0)

    bf16x8 qf[4];
    {
        const __hip_bfloat16* qp = Q + bho + (size_t)(Qw + l31) * HS + hi * 8;
#pragma unroll
        for (int kb = 0; kb < 4; ++kb) qf[kb] = *(const bf16x8*)(qp + kb * 16);
    }
    const int base0 = l31 * 128;
    const int swz0 = ((l31 ^ (l31 >> 3)) & 7) << 4;
    const int r32 = 32 + l31;
    const int base1 = r32 * 128;
    const int swz1 = ((r32 ^ (r32 >> 3)) & 7) << 4;

    float mrow = -1e30f, lsum = 0.f;
    f32x16 o0 = {}, o1 = {};   // O^T: col=q, rows d=crow(+32)

    ASTAGE(0, kt0);
    __syncthreads();
    for (int kt = kt0; kt < ktN; ++kt) {
        const int cur = (kt - kt0) & 1;
        if (kt + 1 < ktN) ASTAGE(cur ^ 1, kt + 1);
        const char* KsB = (const char*)KsBuf[cur];
        const char* VsB = (const char*)VsBuf[cur];
        const int kvb0 = kt * 64, kvb1 = kt * 64 + 32;
        const bool do0 = kvb0 <= Qw;               // wave-uniform
        const bool do1 = kvb1 <= Qw;
        if (do0) {
            f32x16 s0 = {}, s1 = {};
            __builtin_amdgcn_s_setprio(1);
#pragma unroll
            for (int kb = 0; kb < 4; ++kb) {
                bf16x8 kf = *(const bf16x8*)(KsB + base0 + ((kb * 32 + hi * 16) ^ swz0));
                s0 = __builtin_amdgcn_mfma_f32_32x32x16_bf16(kf, qf[kb], s0, 0, 0, 0);
            }
            if (do1) {
#pragma unroll
                for (int kb = 0; kb < 4; ++kb) {
                    bf16x8 kf = *(const bf16x8*)(KsB + base1 + ((kb * 32 + hi * 16) ^ swz1));
                    s1 = __builtin_amdgcn_mfma_f32_32x32x16_bf16(kf, qf[kb], s1, 0, 0, 0);
                }
            }
            __builtin_amdgcn_s_setprio(0);
            if (kvb0 == Qw) {
#pragma unroll
                for (int r = 0; r < 16; ++r) {
                    int crow = (r & 3) + 8 * (r >> 2) + 4 * hi;
                    if (crow > l31) s0[r] = -1e30f;
                }
            }
            if (do1 && kvb1 == Qw) {
#pragma unroll
                for (int r = 0; r < 16; ++r) {
                    int crow = (r & 3) + 8 * (r >> 2) + 4 * hi;
                    if (crow > l31) s1[r] = -1e30f;
                }
            }
            float mx = s0[0];
#pragma unroll
            for (int r = 1; r < 16; ++r) mx = fmaxf(mx, s0[r]);
            if (do1) {
#pragma unroll
                for (int r = 0; r < 16; ++r) mx = fmaxf(mx, s1[r]);
            }
            mx = fmaxf(mx, __shfl_xor(mx, 32));
            const float mn = fmaxf(mrow, mx);
            const float alpha = __builtin_amdgcn_exp2f(mrow - mn);
            mrow = mn;
            float ls = 0.f;
#pragma unroll
            for (int r = 0; r < 16; ++r) { s0[r] = __builtin_amdgcn_exp2f(s0[r] - mn); ls += s0[r]; }
            if (do1) {
#pragma unroll
                for (int r = 0; r < 16; ++r) { s1[r] = __builtin_amdgcn_exp2f(s1[r] - mn); ls += s1[r]; }
            }
            ls += __shfl_xor(ls, 32);
            lsum = lsum * alpha + ls;
            o0 = o0 * alpha;
            o1 = o1 * alpha;
            union { u32 u[4]; bf16x8 v; } pa[4];
            {
                u32 w01 = pk2(s0[0], s0[1]),   w23 = pk2(s0[2], s0[3]);
                u32 w45 = pk2(s0[4], s0[5]),   w67 = pk2(s0[6], s0[7]);
                u32 w89 = pk2(s0[8], s0[9]),   wab = pk2(s0[10], s0[11]);
                u32 wcd = pk2(s0[12], s0[13]), wef = pk2(s0[14], s0[15]);
                u32 xa = __shfl_xor(hi ? w01 : w45, 32);
                u32 xb = __shfl_xor(hi ? w23 : w67, 32);
                u32 xc = __shfl_xor(hi ? w89 : wcd, 32);
                u32 xd = __shfl_xor(hi ? wab : wef, 32);
                if (hi == 0) {
                    pa[0].u[0] = w01; pa[0].u[1] = w23; pa[0].u[2] = xa;  pa[0].u[3] = xb;
                    pa[1].u[0] = w89; pa[1].u[1] = wab; pa[1].u[2] = xc;  pa[1].u[3] = xd;
                } else {
                    pa[0].u[0] = xa;  pa[0].u[1] = xb;  pa[0].u[2] = w45; pa[0].u[3] = w67;
                    pa[1].u[0] = xc;  pa[1].u[1] = xd;  pa[1].u[2] = wcd; pa[1].u[3] = wef;
                }
            }
            if (do1) {
                u32 w01 = pk2(s1[0], s1[1]),   w23 = pk2(s1[2], s1[3]);
                u32 w45 = pk2(s1[4], s1[5]),   w67 = pk2(s1[6], s1[7]);
                u32 w89 = pk2(s1[8], s1[9]),   wab = pk2(s1[10], s1[11]);
                u32 wcd = pk2(s1[12], s1[13]), wef = pk2(s1[14], s1[15]);
                u32 xa = __shfl_xor(hi ? w01 : w45, 32);
                u32 xb = __shfl_xor(hi ? w23 : w67, 32);
                u32 xc = __shfl_xor(hi ? w89 : wcd, 32);
                u32 xd = __shfl_xor(hi ? wab : wef, 32);
                if (hi == 0) {
                    pa[2].u[0] = w01; pa[2].u[1] = w23; pa[2].u[2] = xa;  pa[2].u[3] = xb;
                    pa[3].u[0] = w89; pa[3].u[1] = wab; pa[3].u[2] = xc;  pa[3].u[3] = xd;
                } else {
                    pa[2].u[0] = xa;  pa[2].u[1] = xb;  pa[2].u[2] = w45; pa[2].u[3] = w67;
                    pa[3].u[0] = xc;  pa[3].u[1] = xd;  pa[3].u[2] = wcd; pa[3].u[3] = wef;
                }
            }
            __builtin_amdgcn_s_setprio(1);
#define PVC(ks) do { \
                bf16x8 vf0 = *(const bf16x8*)(VsB + base0 + (((ks) * 32 + hi * 16) ^ swz0)); \
                o0 = __builtin_amdgcn_mfma_f32_32x32x16_bf16(vf0, pa[ks].v, o0, 0, 0, 0); \
                bf16x8 vf1 = *(const bf16x8*)(VsB + base1 + (((ks) * 32 + hi * 16) ^ swz1)); \
                o1 = __builtin_amdgcn_mfma_f32_32x32x16_bf16(vf1, pa[ks].v, o1, 0, 0, 0); } while (0)
            PVC(0); PVC(1);
            if (do1) { PVC(2); PVC(3); }
#undef PVC
            __builtin_amdgcn_s_setprio(0);
        }
        __syncthreads();   // drains prefetch vmcnt + guards buffer reuse
    }
    if (!split) {
        char* T = (char*)KsBuf + w * 4096;
        const float inv = 1.f / lsum;
        const int tsw = (l31 & 7) << 4;
        const int tbase = l31 * 128;
#pragma unroll
        for (int r = 0; r < 16; ++r) {
            int d0 = (r & 3) + 8 * (r >> 2) + 4 * hi;
            *(__hip_bfloat16*)(T + tbase + ((d0 * 2) ^ tsw)) = __float2bfloat16(o0[r] * inv);
            *(__hip_bfloat16*)(T + tbase + (((d0 + 32) * 2) ^ tsw)) = __float2bfloat16(o1[r] * inv);
        }
        const int b = bh >> 4, h = bh & 15;
#pragma unroll
        for (int p = 0; p < 4; ++p) {
            int q = p * 8 + (lane >> 3);
            int colb = ((lane & 7) * 16) ^ ((q & 7) << 4);
            bf16x8 v = *(const bf16x8*)(T + q * 128 + colb);
            *(bf16x8*)(Y + ((size_t)b * TSEQ + Qw + q) * CEMB + h * HS + (lane & 7) * 8) = v;
        }
    } else {
        const int p = bh * (DEEP ? 28 : 16) + pslot;
        float* Ob = Op + (size_t)p * 8192;
        const int qloc = w * 32 + l31;
#pragma unroll
        for (int r = 0; r < 16; ++r) {
            int d0 = (r & 3) + 8 * (r >> 2) + 4 * hi;
            Ob[d0 * 128 + qloc] = o0[r];
            Ob[(d0 + 32) * 128 + qloc] = o1[r];
        }
        if (hi == 0) {
            Mp[p * 128 + qloc] = mrow;
            Lp[p * 128 + qloc] = lsum;
        }
    }
#undef ASTAGE
}

// ---------------- split-K merge (24-unit: 2-way, qbb 8..15) ----------------
__global__ __launch_bounds__(256) void merge_k(
    const float* __restrict__ Op, const float* __restrict__ Mp,
    const float* __restrict__ Lp, __hip_bfloat16* __restrict__ Y)
{
    const int blk = blockIdx.x;
    const int bh = blk & 31, qq = blk >> 5;
    const int p0 = bh * 16 + qq * 2, p1 = p0 + 1;
    const int t = threadIdx.x;
    const int q = t >> 1, dg = (t & 1) * 32;
    const float m0 = Mp[p0 * 128 + q], m1 = Mp[p1 * 128 + q];
    const float l0 = Lp[p0 * 128 + q], l1 = Lp[p1 * 128 + q];
    const float m = fmaxf(m0, m1);
    const float w0 = exp2f(m0 - m), w1 = exp2f(m1 - m);
    const float inv = 1.f / (l0 * w0 + l1 * w1);
    const float* O0 = Op + (size_t)p0 * 8192;
    const float* O1 = Op + (size_t)p1 * 8192;
    union { bf16x8 v[4]; __hip_bfloat16 h[32]; } outp;
#pragma unroll
    for (int i = 0; i < 32; ++i) {
        int d = dg + i;
        outp.h[i] = __float2bfloat16((O0[d * 128 + q] * w0 + O1[d * 128 + q] * w1) * inv);
    }
    const int b = bh >> 4, h = bh & 15;
    const int qg = (8 + qq) * 128 + q;
    __hip_bfloat16* yp = Y + ((size_t)b * TSEQ + qg) * CEMB + h * HS + dg;
#pragma unroll
    for (int i = 0; i < 4; ++i) *(bf16x8*)(yp + i * 8) = outp.v[i];
}

// ---------------- split-K merge (32-unit: qbb 4..11 2-way, 12..15 3-way) ---
__global__ __launch_bounds__(256) void merge_deep_k(
    const float* __restrict__ Op, const float* __restrict__ Mp,
    const float* __restrict__ Lp, __hip_bfloat16* __restrict__ Y)
{
    const int blk = blockIdx.x;          // 384 = 32 bh x 12 qi
    const int bh = blk & 31, qi = blk >> 5;   // qbb = 4 + qi
    const int np = (qi < 8) ? 2 : 3;
    const int p0 = bh * 28 + ((qi < 8) ? qi * 2 : 16 + (qi - 8) * 3);
    const int t = threadIdx.x;
    const int q = t >> 1, dg = (t & 1) * 32;
    float m0 = Mp[p0 * 128 + q], m1 = Mp[(p0 + 1) * 128 + q];
    float l0 = Lp[p0 * 128 + q], l1 = Lp[(p0 + 1) * 128 + q];
    float m2 = -1e30f, l2 = 0.f;
    if (np == 3) { m2 = Mp[(p0 + 2) * 128 + q]; l2 = Lp[(p0 + 2) * 128 + q]; }
    const float m = fmaxf(fmaxf(m0, m1), m2);
    const float w0 = exp2f(m0 - m), w1 = exp2f(m1 - m);
    const float w2 = (np == 3) ? exp2f(m2 - m) : 0.f;
    const float inv = 1.f / (l0 * w0 + l1 * w1 + l2 * w2);
    const float* O0 = Op + (size_t)p0 * 8192;
    const float* O1 = O0 + 8192;
    const float* O2 = O1 + 8192;
    union { bf16x8 v[4]; __hip_bfloat16 h[32]; } outp;
#pragma unroll
    for (int i = 0; i < 32; ++i) {
        int d = dg + i;
        float acc = O0[d * 128 + q] * w0 + O1[d * 128 + q] * w1;
        if (np == 3) acc += O2[d * 128 + q] * w2;
        outp.h[i] = __float2bfloat16(acc * inv);
    }
    const int b = bh >> 4, h = bh & 15;
    const int qg = (4 + qi) * 128 + q;
    __hip_bfloat16* yp = Y + ((size_t)b * TSEQ + qg) * CEMB + h * HS + dg;
#pragma unroll
    for (int i = 0; i < 4; ++i) *(bf16x8*)(yp + i * 8) = outp.v[i];
}

// ---------------- Output projection, bf16 MFMA, 128x64 tile ----------------
__global__ __launch_bounds__(256) void proj_mfma_k(
    const __hip_bfloat16* __restrict__ Ab, const __hip_bfloat16* __restrict__ Wt,
    const float* __restrict__ bias, float* __restrict__ out)
{
    __shared__ __hip_bfloat16 Al[2][128 * 32];
    __shared__ __hip_bfloat16 Bl[2][64 * 32];
    const int tid = threadIdx.x;
    const int lane = tid & 63, w = tid >> 6;
    const int lr = lane & 15, lg = lane >> 4;
    const int wm = w >> 1, wn = w & 1;
    const int n0 = blockIdx.x * 64;
    const int m0 = blockIdx.y * 128;
    const __hip_bfloat16* gA = Ab + (size_t)(m0 + (tid >> 2)) * CEMB + (tid & 3) * 8;
    const __hip_bfloat16* gB = Wt + (size_t)(n0 + (tid >> 2)) * CEMB + (tid & 3) * 8;
#define PSTAGE(buf, kk) do { \
        gload16(gA + (kk), &Al[buf][tid * 8]); \
        gload16(gA + 64 * CEMB + (kk), &Al[buf][2048 + tid * 8]); \
        gload16(gB + (kk), &Bl[buf][tid * 8]); } while (0)
    f32x4 acc[4][2] = {};
    PSTAGE(0, 0);
    __syncthreads();
    for (int k0 = 0; k0 < CEMB; k0 += 32) {
        const int cur = (k0 >> 5) & 1;
        if (k0 + 32 < CEMB) PSTAGE(cur ^ 1, k0 + 32);
        bf16x8 af[4], bfr[2];
#pragma unroll
        for (int mi = 0; mi < 4; ++mi)
            af[mi] = *(const bf16x8*)&Al[cur][(wm * 64 + mi * 16 + lr) * 32 + lg * 8];
#pragma unroll
        for (int ni = 0; ni < 2; ++ni)
            bfr[ni] = *(const bf16x8*)&Bl[cur][(wn * 32 + ni * 16 + lr) * 32 + lg * 8];
#pragma unroll
        for (int mi = 0; mi < 4; ++mi)
#pragma unroll
            for (int ni = 0; ni < 2; ++ni)
                acc[mi][ni] = __builtin_amdgcn_mfma_f32_16x16x32_bf16(af[mi], bfr[ni], acc[mi][ni], 0, 0, 0);
        __syncthreads();
    }
#pragma unroll
    for (int mi = 0; mi < 4; ++mi) {
#pragma unroll
        for (int ni = 0; ni < 2; ++ni) {
            const int gcol = n0 + wn * 32 + ni * 16 + lr;
            const float bv = bias[gcol];
            const int growb = m0 + wm * 64 + mi * 16 + lg * 4;
#pragma unroll
            for (int r = 0; r < 4; ++r)
                out[(size_t)(growb + r) * CEMB + gcol] = acc[mi][ni][r] + bv;
        }
    }
#undef PSTAGE
}

extern "C" void kernel_launch(void* const* d_in, const int* in_sizes, int n_in,
                              void* d_out, int out_size, void* d_ws, size_t ws_size,
                              hipStream_t stream)
{
    const float* x      = (const float*)d_in[0];
    const float* w_attn = (const float*)d_in[1];
    const float* b_attn = (const float*)d_in[2];
    const float* w_proj = (const float*)d_in[3];
    const float* b_proj = (const float*)d_in[4];
    float* out = (float*)d_out;
    char* base = (char*)d_ws;

    const size_t MB = 1048576;
    float* tbl          = (float*)base;                              // 4 KB
    __hip_bfloat16* Xb  = (__hip_bfloat16*)(base + 4096);            // 8 MB (reused as Yb)
    __hip_bfloat16* Wta = (__hip_bfloat16*)(base + 4096 + 8 * MB);   // 6 MB
    __hip_bfloat16* Wpt = (__hip_bfloat16*)(base + 4096 + 14 * MB);  // 2 MB
    __hip_bfloat16* Qb  = (__hip_bfloat16*)(base + 4096 + 16 * MB);  // 8 MB
    __hip_bfloat16* Kb  = (__hip_bfloat16*)(base + 4096 + 24 * MB);  // 8 MB
    __hip_bfloat16* Vtb = (__hip_bfloat16*)(base + 4096 + 32 * MB);  // 8 MB
    __hip_bfloat16* Yb  = Xb;
    const size_t PART_OFF = 4096 + 40 * MB;
    float* Op = (float*)(base + PART_OFF);
    // deep: 896 partials (28/bh); shallow: 512 (16/bh)
    const size_t NP_DEEP = 896, NP_OLD = 512;
    float* MpD = Op + NP_DEEP * 8192;
    float* LpD = MpD + NP_DEEP * 128;
    float* MpO = Op + NP_OLD * 8192;
    float* LpO = MpO + NP_OLD * 128;
    const size_t need_deep = PART_OFF + NP_DEEP * 8192 * 4 + 2 * NP_DEEP * 128 * 4;

    prep_k<<<6145, 256, 0, stream>>>(x, Xb, tbl, w_attn, Wta, w_proj, Wpt);
    qkv_mfma_k<<<dim3(24, 32), 256, 0, stream>>>(Xb, Wta, b_attn, tbl, Qb, Kb, Vtb);
    if (ws_size >= need_deep) {
        attn_split_k<1><<<1024, 256, 0, stream>>>(Qb, Kb, Vtb, Yb, Op, MpD, LpD);
        merge_deep_k<<<384, 256, 0, stream>>>(Op, MpD, LpD, Yb);
    } else {
        attn_split_k<0><<<768, 256, 0, stream>>>(Qb, Kb, Vtb, Yb, Op, MpO, LpO);
        merge_k<<<256, 256, 0, stream>>>(Op, MpO, LpO, Yb);
    }
    proj_mfma_k<<<dim3(16, 32), 256, 0, stream>>>(Yb, Wpt, b_proj, out);
}

// Round 17
// 121.289 us; speedup vs baseline: 1.1692x; 1.1692x over previous
//
#include <hip/hip_runtime.h>
#include <hip/hip_bf16.h>
#include <math.h>

#define TSEQ 2048
#define CEMB 1024
#define NHEAD 16
#define HS 64

typedef __attribute__((ext_vector_type(8))) short bf16x8;
typedef __attribute__((ext_vector_type(4))) float f32x4;
typedef __attribute__((ext_vector_type(16))) float f32x16;
typedef unsigned int u32;
typedef unsigned long long u64;
typedef unsigned short u16;

__device__ __forceinline__ void gload16(const void* g, void* l) {
    __builtin_amdgcn_global_load_lds(
        (const __attribute__((address_space(1))) unsigned int*)g,
        (__attribute__((address_space(3))) unsigned int*)l, 16, 0, 0);
}

__device__ __forceinline__ u32 pk2(float a, float b) {
    union { u32 u; __hip_bfloat16 h[2]; } t;
    t.h[0] = __float2bfloat16(a); t.h[1] = __float2bfloat16(b);
    return t.u;
}

__device__ __forceinline__ u16 bf16u(float a) {
    union { u16 u; __hip_bfloat16 h; } t;
    t.h = __float2bfloat16(a);
    return t.u;
}

// unit table: upos -> unit, snake-balanced so each CU's 3 units sum to 34 rounds
__device__ const int UNIT_TBL[24] = {22,7,20,21,19,17,6,14,
                                     23,18,16,12,4,5,13,15,
                                     0,1,2,3,10,8,9,11};

// ---------------- fused prep: x->bf16, RoPE table, both weight transposes ---
// Reference quirk: _apply_rope uses cache[:d1] where d1 = n_head after the
// transpose, so the rotation angle is head_index * theta_j (constant over t).
__device__ __forceinline__ void transpose_tile(const float* __restrict__ src,
                                               __hip_bfloat16* __restrict__ dst,
                                               int K, int N, int n0, int k0) {
    __shared__ float tile[32][33];
    int tx = threadIdx.x & 31, ty = threadIdx.x >> 5;
#pragma unroll
    for (int i = 0; i < 32; i += 8)
        tile[ty + i][tx] = src[(size_t)(k0 + ty + i) * N + n0 + tx];
    __syncthreads();
#pragma unroll
    for (int i = 0; i < 32; i += 8)
        dst[(size_t)(n0 + ty + i) * K + k0 + tx] = __float2bfloat16(tile[tx][ty + i]);
}

__global__ __launch_bounds__(256) void prep_k(
    const float* __restrict__ x, __hip_bfloat16* __restrict__ Xb,
    float* __restrict__ tbl,
    const float* __restrict__ w_attn, __hip_bfloat16* __restrict__ Wta,
    const float* __restrict__ w_proj, __hip_bfloat16* __restrict__ Wpt)
{
    const int id = blockIdx.x;
    if (id < 2048) {
        int i = (id * 256 + threadIdx.x) * 8;
        float4 a = *(const float4*)(x + i);
        float4 b = *(const float4*)(x + i + 4);
        union { bf16x8 v; __hip_bfloat16 h[8]; } pk;
        pk.h[0] = __float2bfloat16(a.x); pk.h[1] = __float2bfloat16(a.y);
        pk.h[2] = __float2bfloat16(a.z); pk.h[3] = __float2bfloat16(a.w);
        pk.h[4] = __float2bfloat16(b.x); pk.h[5] = __float2bfloat16(b.y);
        pk.h[6] = __float2bfloat16(b.z); pk.h[7] = __float2bfloat16(b.w);
        *(bf16x8*)(Xb + i) = pk.v;
    } else if (id == 2048) {
#pragma unroll
        for (int it = 0; it < 2; ++it) {
            int idx = threadIdx.x + 256 * it;
            int h = idx >> 5, j = idx & 31;
            double theta = pow(10000.0, -2.0 * (double)j / 1024.0);
            double ang = (double)h * theta;
            tbl[2 * idx + 0] = (float)cos(ang);
            tbl[2 * idx + 1] = (float)sin(ang);
        }
    } else if (id < 2049 + 3072) {
        int t = id - 2049;
        transpose_tile(w_attn, Wta, CEMB, 3 * CEMB, (t % 96) * 32, (t / 96) * 32);
    } else {
        int t = id - (2049 + 3072);
        transpose_tile(w_proj, Wpt, CEMB, CEMB, (t & 31) * 32, (t >> 5) * 32);
    }
}

// ---------------- QKV GEMM, bf16 MFMA, RoPE epilogue ----------------
__global__ __launch_bounds__(256) void qkv_mfma_k(
    const __hip_bfloat16* __restrict__ Xb, const __hip_bfloat16* __restrict__ Wt,
    const float* __restrict__ bias, const float* __restrict__ tbl,
    __hip_bfloat16* __restrict__ Qb, __hip_bfloat16* __restrict__ Kb,
    __hip_bfloat16* __restrict__ Vtb)
{
    __shared__ __hip_bfloat16 SM[4][128 * 32];   // A dbuf = SM[0..1], B dbuf = SM[2..3]
    const int tid = threadIdx.x;
    const int lane = tid & 63, w = tid >> 6;
    const int lr = lane & 15, lg = lane >> 4;
    const int wm = w >> 1, wn = w & 1;
    const int n0 = blockIdx.x * 128;
    const int m0 = blockIdx.y * 128;
    const __hip_bfloat16* gA = Xb + (size_t)(m0 + (tid >> 2)) * CEMB + (tid & 3) * 8;
    const __hip_bfloat16* gB = Wt + (size_t)(n0 + (tid >> 2)) * CEMB + (tid & 3) * 8;
#define QSTAGE(buf, kk) do { \
        gload16(gA + (kk), &SM[buf][tid * 8]); \
        gload16(gA + 64 * CEMB + (kk), &SM[buf][2048 + tid * 8]); \
        gload16(gB + (kk), &SM[2 + (buf)][tid * 8]); \
        gload16(gB + 64 * CEMB + (kk), &SM[2 + (buf)][2048 + tid * 8]); } while (0)
    f32x4 acc[4][4] = {};
    QSTAGE(0, 0);
    __syncthreads();
    for (int k0 = 0; k0 < CEMB; k0 += 32) {
        const int cur = (k0 >> 5) & 1;
        if (k0 + 32 < CEMB) QSTAGE(cur ^ 1, k0 + 32);
        bf16x8 af[4], bfr[4];
#pragma unroll
        for (int mi = 0; mi < 4; ++mi)
            af[mi] = *(const bf16x8*)&SM[cur][(wm * 64 + mi * 16 + lr) * 32 + lg * 8];
#pragma unroll
        for (int ni = 0; ni < 4; ++ni)
            bfr[ni] = *(const bf16x8*)&SM[2 + cur][(wn * 64 + ni * 16 + lr) * 32 + lg * 8];
#pragma unroll
        for (int mi = 0; mi < 4; ++mi)
#pragma unroll
            for (int ni = 0; ni < 4; ++ni)
                acc[mi][ni] = __builtin_amdgcn_mfma_f32_16x16x32_bf16(af[mi], bfr[ni], acc[mi][ni], 0, 0, 0);
        __syncthreads();
    }
    const int sec = (n0 >> 10);
    const int bb = m0 >> 11;
    const int t0v = m0 & 2047;
    const int h0 = (n0 & 1023) >> 6;
    if (sec == 2) {
        char* T = (char*)SM;   // [128 n][128 m] bf16, row stride 256B
#pragma unroll
        for (int mi = 0; mi < 4; ++mi) {
#pragma unroll
            for (int ni = 0; ni < 4; ++ni) {
                const int nl = wn * 64 + ni * 16 + lr;
                const float bv = bias[n0 + nl];
                const int mb = wm * 64 + mi * 16 + lg * 4;
                union { u64 u; __hip_bfloat16 hh[4]; } pk;
#pragma unroll
                for (int r = 0; r < 4; ++r) pk.hh[r] = __float2bfloat16(acc[mi][ni][r] + bv);
                *(u64*)(T + nl * 256 + ((mb * 2) ^ ((nl & 7) << 4))) = pk.u;
            }
        }
        __syncthreads();
#pragma unroll
        for (int i = 0; i < 8; ++i) {
            int cid = tid + 256 * i;
            int n = cid >> 4, mc = cid & 15;
            bf16x8 v = *(const bf16x8*)(T + n * 256 + ((mc * 16) ^ ((n & 7) << 4)));
            *(bf16x8*)&Vtb[(((size_t)bb * NHEAD + h0 + (n >> 6)) * HS + (n & 63)) * TSEQ + t0v + mc * 8] = v;
        }
    } else {
        char* T = (char*)SM;   // [128 m][128 n] bf16, row stride 256B
        const float sc = (sec == 0) ? 0.18033688011112042f : 1.0f;  // 1/8*log2e for Q
        __hip_bfloat16* dst = (sec == 0) ? Qb : Kb;
#pragma unroll
        for (int mi = 0; mi < 4; ++mi) {
#pragma unroll
            for (int ni = 0; ni < 4; ++ni) {
                const int nl = wn * 64 + ni * 16 + lr;
                const int c63 = (n0 + nl) & 63;
                const int h = h0 + (nl >> 6);
                const int j = c63 >> 1;
                const float cth = tbl[(h * 32 + j) * 2 + 0];
                const float sth = tbl[(h * 32 + j) * 2 + 1];
                const float bv = bias[n0 + nl];
                const int mb = wm * 64 + mi * 16 + lg * 4;
#pragma unroll
                for (int r = 0; r < 4; ++r) {
                    float val = acc[mi][ni][r] + bv;
                    float prt = __shfl_xor(val, 1);
                    float rot = (lr & 1) ? (val * cth + prt * sth) : (val * cth - prt * sth);
                    const int row = mb + r;
                    *(u16*)(T + row * 256 + ((nl * 2) ^ ((row & 7) << 4))) = bf16u(rot * sc);
                }
            }
        }
        __syncthreads();
#pragma unroll
        for (int i = 0; i < 8; ++i) {
            int cid = tid + 256 * i;
            int row = cid >> 4, nc = cid & 15;
            bf16x8 v = *(const bf16x8*)(T + row * 256 + ((nc * 16) ^ ((row & 7) << 4)));
            int col = nc * 8;
            *(bf16x8*)&dst[(((size_t)bb * NHEAD + h0 + (col >> 6)) * TSEQ + t0v + row) * HS + (col & 63)] = v;
        }
    }
#undef QSTAGE
}

// ---------------- split-K flash attention (R11/R15-proven body) -------------
// 768 blocks = 32 bh x 24 units; 4 waves x 32 q = 128 q rows/block; KV tile 64.
// Unit u<8: unsplit qbb=u (tiles [0,2u+2)), writes Y. u>=8: half of qbb=8..15
// (qbb+1 tiles), writes unnormalized bf16 O^T + (m,l) partials; merge_k combines.
__global__ __launch_bounds__(256) void attn_split_k(
    const __hip_bfloat16* __restrict__ Q, const __hip_bfloat16* __restrict__ K,
    const __hip_bfloat16* __restrict__ Vt, __hip_bfloat16* __restrict__ Y,
    __hip_bfloat16* __restrict__ Op, float* __restrict__ Mp, float* __restrict__ Lp)
{
    __shared__ __hip_bfloat16 KsBuf[2][64 * 64];   // [kv][hs], swizzled
    __shared__ __hip_bfloat16 VsBuf[2][64 * 64];   // [hs][kv], swizzled
    const int tid = threadIdx.x;                   // 0..255
    const int w = tid >> 6;
    const int lane = tid & 63;
    const int l31 = lane & 31;
    const int hi = lane >> 5;
    const int id = blockIdx.x;
    const int bh = id & 31;
    const int u = UNIT_TBL[id >> 5];
    int qbb, kt0, ktN, half;
    bool split;
    if (u < 8) { qbb = u; half = 0; kt0 = 0; ktN = 2 * u + 2; split = false; }
    else {
        qbb = 8 + ((u - 8) >> 1); half = (u - 8) & 1;
        kt0 = half ? (qbb + 1) : 0;
        ktN = half ? (2 * qbb + 2) : (qbb + 1);
        split = true;
    }
    const size_t bho = (size_t)bh * TSEQ * HS;
    const int Qw = qbb * 128 + w * 32;             // global q base of this wave

    int srcK[2], srcV[2];
#pragma unroll
    for (int j = 0; j < 2; ++j) {
        int L = (tid + 256 * j) * 16;
        int row = L >> 7;
        int ce = ((L & 127) ^ (((row ^ (row >> 3)) & 7) << 4)) >> 1;
        srcK[j] = row * HS + ce;
        srcV[j] = row * TSEQ + ce;
    }
    const __hip_bfloat16* Kg = K + bho;
    const __hip_bfloat16* Vg = Vt + bho;
#define ASTAGE(buf, kt_) do { \
        const __hip_bfloat16* kg_ = Kg + (size_t)(kt_) * 64 * HS; \
        const __hip_bfloat16* vg_ = Vg + (size_t)(kt_) * 64; \
        char* kb_ = (char*)KsBuf[buf]; char* vb_ = (char*)VsBuf[buf]; \
        _Pragma("unroll") \
        for (int j = 0; j < 2; ++j) { \
            gload16(kg_ + srcK[j], kb_ + (tid + 256 * j) * 16); \
            gload16(vg_ + srcV[j], vb_ + (tid + 256 * j) * 16); } } while (0)

    bf16x8 qf[4];
    {
        const __hip_bfloat16* qp = Q + bho + (size_t)(Qw + l31) * HS + hi * 8;
#pragma unroll
        for (int kb = 0; kb < 4; ++kb) qf[kb] = *(const bf16x8*)(qp + kb * 16);
    }
    const int base0 = l31 * 128;
    const int swz0 = ((l31 ^ (l31 >> 3)) & 7) << 4;
    const int r32 = 32 + l31;
    const int base1 = r32 * 128;
    const int swz1 = ((r32 ^ (r32 >> 3)) & 7) << 4;

    float mrow = -1e30f, lsum = 0.f;
    f32x16 o0 = {}, o1 = {};   // O^T: col=q, rows d=crow(+32)

    ASTAGE(0, kt0);
    __syncthreads();
    for (int kt = kt0; kt < ktN; ++kt) {
        const int cur = (kt - kt0) & 1;
        if (kt + 1 < ktN) ASTAGE(cur ^ 1, kt + 1);
        const char* KsB = (const char*)KsBuf[cur];
        const char* VsB = (const char*)VsBuf[cur];
        const int kvb0 = kt * 64, kvb1 = kt * 64 + 32;
        const bool do0 = kvb0 <= Qw;               // wave-uniform
        const bool do1 = kvb1 <= Qw;
        if (do0) {
            f32x16 s0 = {}, s1 = {};
            __builtin_amdgcn_s_setprio(1);
#pragma unroll
            for (int kb = 0; kb < 4; ++kb) {
                bf16x8 kf = *(const bf16x8*)(KsB + base0 + ((kb * 32 + hi * 16) ^ swz0));
                s0 = __builtin_amdgcn_mfma_f32_32x32x16_bf16(kf, qf[kb], s0, 0, 0, 0);
            }
            if (do1) {
#pragma unroll
                for (int kb = 0; kb < 4; ++kb) {
                    bf16x8 kf = *(const bf16x8*)(KsB + base1 + ((kb * 32 + hi * 16) ^ swz1));
                    s1 = __builtin_amdgcn_mfma_f32_32x32x16_bf16(kf, qf[kb], s1, 0, 0, 0);
                }
            }
            __builtin_amdgcn_s_setprio(0);
            if (kvb0 == Qw) {
#pragma unroll
                for (int r = 0; r < 16; ++r) {
                    int crow = (r & 3) + 8 * (r >> 2) + 4 * hi;
                    if (crow > l31) s0[r] = -1e30f;
                }
            }
            if (do1 && kvb1 == Qw) {
#pragma unroll
                for (int r = 0; r < 16; ++r) {
                    int crow = (r & 3) + 8 * (r >> 2) + 4 * hi;
                    if (crow > l31) s1[r] = -1e30f;
                }
            }
            float mx = s0[0];
#pragma unroll
            for (int r = 1; r < 16; ++r) mx = fmaxf(mx, s0[r]);
            if (do1) {
#pragma unroll
                for (int r = 0; r < 16; ++r) mx = fmaxf(mx, s1[r]);
            }
            mx = fmaxf(mx, __shfl_xor(mx, 32));
            const float mn = fmaxf(mrow, mx);
            const float alpha = __builtin_amdgcn_exp2f(mrow - mn);
            mrow = mn;
            float ls = 0.f;
#pragma unroll
            for (int r = 0; r < 16; ++r) { s0[r] = __builtin_amdgcn_exp2f(s0[r] - mn); ls += s0[r]; }
            if (do1) {
#pragma unroll
                for (int r = 0; r < 16; ++r) { s1[r] = __builtin_amdgcn_exp2f(s1[r] - mn); ls += s1[r]; }
            }
            ls += __shfl_xor(ls, 32);
            lsum = lsum * alpha + ls;
            o0 = o0 * alpha;
            o1 = o1 * alpha;
            union { u32 u[4]; bf16x8 v; } pa[4];
            {
                u32 w01 = pk2(s0[0], s0[1]),   w23 = pk2(s0[2], s0[3]);
                u32 w45 = pk2(s0[4], s0[5]),   w67 = pk2(s0[6], s0[7]);
                u32 w89 = pk2(s0[8], s0[9]),   wab = pk2(s0[10], s0[11]);
                u32 wcd = pk2(s0[12], s0[13]), wef = pk2(s0[14], s0[15]);
                u32 xa = __shfl_xor(hi ? w01 : w45, 32);
                u32 xb = __shfl_xor(hi ? w23 : w67, 32);
                u32 xc = __shfl_xor(hi ? w89 : wcd, 32);
                u32 xd = __shfl_xor(hi ? wab : wef, 32);
                if (hi == 0) {
                    pa[0].u[0] = w01; pa[0].u[1] = w23; pa[0].u[2] = xa;  pa[0].u[3] = xb;
                    pa[1].u[0] = w89; pa[1].u[1] = wab; pa[1].u[2] = xc;  pa[1].u[3] = xd;
                } else {
                    pa[0].u[0] = xa;  pa[0].u[1] = xb;  pa[0].u[2] = w45; pa[0].u[3] = w67;
                    pa[1].u[0] = xc;  pa[1].u[1] = xd;  pa[1].u[2] = wcd; pa[1].u[3] = wef;
                }
            }
            if (do1) {
                u32 w01 = pk2(s1[0], s1[1]),   w23 = pk2(s1[2], s1[3]);
                u32 w45 = pk2(s1[4], s1[5]),   w67 = pk2(s1[6], s1[7]);
                u32 w89 = pk2(s1[8], s1[9]),   wab = pk2(s1[10], s1[11]);
                u32 wcd = pk2(s1[12], s1[13]), wef = pk2(s1[14], s1[15]);
                u32 xa = __shfl_xor(hi ? w01 : w45, 32);
                u32 xb = __shfl_xor(hi ? w23 : w67, 32);
                u32 xc = __shfl_xor(hi ? w89 : wcd, 32);
                u32 xd = __shfl_xor(hi ? wab : wef, 32);
                if (hi == 0) {
                    pa[2].u[0] = w01; pa[2].u[1] = w23; pa[2].u[2] = xa;  pa[2].u[3] = xb;
                    pa[3].u[0] = w89; pa[3].u[1] = wab; pa[3].u[2] = xc;  pa[3].u[3] = xd;
                } else {
                    pa[2].u[0] = xa;  pa[2].u[1] = xb;  pa[2].u[2] = w45; pa[2].u[3] = w67;
                    pa[3].u[0] = xc;  pa[3].u[1] = xd;  pa[3].u[2] = wcd; pa[3].u[3] = wef;
                }
            }
            __builtin_amdgcn_s_setprio(1);
#define PVC(ks) do { \
                bf16x8 vf0 = *(const bf16x8*)(VsB + base0 + (((ks) * 32 + hi * 16) ^ swz0)); \
                o0 = __builtin_amdgcn_mfma_f32_32x32x16_bf16(vf0, pa[ks].v, o0, 0, 0, 0); \
                bf16x8 vf1 = *(const bf16x8*)(VsB + base1 + (((ks) * 32 + hi * 16) ^ swz1)); \
                o1 = __builtin_amdgcn_mfma_f32_32x32x16_bf16(vf1, pa[ks].v, o1, 0, 0, 0); } while (0)
            PVC(0); PVC(1);
            if (do1) { PVC(2); PVC(3); }
#undef PVC
            __builtin_amdgcn_s_setprio(0);
        }
        __syncthreads();   // drains prefetch vmcnt + guards buffer reuse
    }
    if (!split) {
        char* T = (char*)KsBuf + w * 4096;
        const float inv = 1.f / lsum;
        const int tsw = (l31 & 7) << 4;
        const int tbase = l31 * 128;
#pragma unroll
        for (int r = 0; r < 16; ++r) {
            int d0 = (r & 3) + 8 * (r >> 2) + 4 * hi;
            *(__hip_bfloat16*)(T + tbase + ((d0 * 2) ^ tsw)) = __float2bfloat16(o0[r] * inv);
            *(__hip_bfloat16*)(T + tbase + (((d0 + 32) * 2) ^ tsw)) = __float2bfloat16(o1[r] * inv);
        }
        const int b = bh >> 4, h = bh & 15;
#pragma unroll
        for (int p = 0; p < 4; ++p) {
            int q = p * 8 + (lane >> 3);
            int colb = ((lane & 7) * 16) ^ ((q & 7) << 4);
            bf16x8 v = *(const bf16x8*)(T + q * 128 + colb);
            *(bf16x8*)(Y + ((size_t)b * TSEQ + Qw + q) * CEMB + h * HS + (lane & 7) * 8) = v;
        }
    } else {
        // unnormalized bf16 partial O^T [64 d][128 q] + f32 (m,l)
        const int p = bh * 16 + (qbb - 8) * 2 + half;
        __hip_bfloat16* Ob = Op + (size_t)p * 8192;
        const int qloc = w * 32 + l31;
#pragma unroll
        for (int r = 0; r < 16; ++r) {
            int d0 = (r & 3) + 8 * (r >> 2) + 4 * hi;
            Ob[d0 * 128 + qloc] = __float2bfloat16(o0[r]);
            Ob[(d0 + 32) * 128 + qloc] = __float2bfloat16(o1[r]);
        }
        if (hi == 0) {
            Mp[p * 128 + qloc] = mrow;
            Lp[p * 128 + qloc] = lsum;
        }
    }
#undef ASTAGE
}

// ---------------- split-K merge (bf16 partials) ----------------
__global__ __launch_bounds__(256) void merge_k(
    const __hip_bfloat16* __restrict__ Op, const float* __restrict__ Mp,
    const float* __restrict__ Lp, __hip_bfloat16* __restrict__ Y)
{
    const int blk = blockIdx.x;
    const int bh = blk & 31, qq = blk >> 5;
    const int p0 = bh * 16 + qq * 2, p1 = p0 + 1;
    const int t = threadIdx.x;
    const int q = t >> 1, dg = (t & 1) * 32;
    const float m0 = Mp[p0 * 128 + q], m1 = Mp[p1 * 128 + q];
    const float l0 = Lp[p0 * 128 + q], l1 = Lp[p1 * 128 + q];
    const float m = fmaxf(m0, m1);
    const float w0 = exp2f(m0 - m), w1 = exp2f(m1 - m);
    const float inv = 1.f / (l0 * w0 + l1 * w1);
    const __hip_bfloat16* O0 = Op + (size_t)p0 * 8192;
    const __hip_bfloat16* O1 = Op + (size_t)p1 * 8192;
    union { bf16x8 v[4]; __hip_bfloat16 h[32]; } outp;
#pragma unroll
    for (int i = 0; i < 32; ++i) {
        int d = dg + i;
        float a = __bfloat162float(O0[d * 128 + q]);
        float b = __bfloat162float(O1[d * 128 + q]);
        outp.h[i] = __float2bfloat16((a * w0 + b * w1) * inv);
    }
    const int b2 = bh >> 4, h = bh & 15;
    const int qg = (8 + qq) * 128 + q;
    __hip_bfloat16* yp = Y + ((size_t)b2 * TSEQ + qg) * CEMB + h * HS + dg;
#pragma unroll
    for (int i = 0; i < 4; ++i) *(bf16x8*)(yp + i * 8) = outp.v[i];
}

// ---------------- Output projection, bf16 MFMA, 128x64 tile ----------------
// Grid (16,32) = 512 blocks = 2 blocks/CU (2 waves/SIMD TLP).
__global__ __launch_bounds__(256) void proj_mfma_k(
    const __hip_bfloat16* __restrict__ Ab, const __hip_bfloat16* __restrict__ Wt,
    const float* __restrict__ bias, float* __restrict__ out)
{
    __shared__ __hip_bfloat16 Al[2][128 * 32];
    __shared__ __hip_bfloat16 Bl[2][64 * 32];
    const int tid = threadIdx.x;
    const int lane = tid & 63, w = tid >> 6;
    const int lr = lane & 15, lg = lane >> 4;
    const int wm = w >> 1, wn = w & 1;
    const int n0 = blockIdx.x * 64;
    const int m0 = blockIdx.y * 128;
    const __hip_bfloat16* gA = Ab + (size_t)(m0 + (tid >> 2)) * CEMB + (tid & 3) * 8;
    const __hip_bfloat16* gB = Wt + (size_t)(n0 + (tid >> 2)) * CEMB + (tid & 3) * 8;
#define PSTAGE(buf, kk) do { \
        gload16(gA + (kk), &Al[buf][tid * 8]); \
        gload16(gA + 64 * CEMB + (kk), &Al[buf][2048 + tid * 8]); \
        gload16(gB + (kk), &Bl[buf][tid * 8]); } while (0)
    f32x4 acc[4][2] = {};
    PSTAGE(0, 0);
    __syncthreads();
    for (int k0 = 0; k0 < CEMB; k0 += 32) {
        const int cur = (k0 >> 5) & 1;
        if (k0 + 32 < CEMB) PSTAGE(cur ^ 1, k0 + 32);
        bf16x8 af[4], bfr[2];
#pragma unroll
        for (int mi = 0; mi < 4; ++mi)
            af[mi] = *(const bf16x8*)&Al[cur][(wm * 64 + mi * 16 + lr) * 32 + lg * 8];
#pragma unroll
        for (int ni = 0; ni < 2; ++ni)
            bfr[ni] = *(const bf16x8*)&Bl[cur][(wn * 32 + ni * 16 + lr) * 32 + lg * 8];
#pragma unroll
        for (int mi = 0; mi < 4; ++mi)
#pragma unroll
            for (int ni = 0; ni < 2; ++ni)
                acc[mi][ni] = __builtin_amdgcn_mfma_f32_16x16x32_bf16(af[mi], bfr[ni], acc[mi][ni], 0, 0, 0);
        __syncthreads();
    }
#pragma unroll
    for (int mi = 0; mi < 4; ++mi) {
#pragma unroll
        for (int ni = 0; ni < 2; ++ni) {
            const int gcol = n0 + wn * 32 + ni * 16 + lr;
            const float bv = bias[gcol];
            const int growb = m0 + wm * 64 + mi * 16 + lg * 4;
#pragma unroll
            for (int r = 0; r < 4; ++r)
                out[(size_t)(growb + r) * CEMB + gcol] = acc[mi][ni][r] + bv;
        }
    }
#undef PSTAGE
}

extern "C" void kernel_launch(void* const* d_in, const int* in_sizes, int n_in,
                              void* d_out, int out_size, void* d_ws, size_t ws_size,
                              hipStream_t stream)
{
    const float* x      = (const float*)d_in[0];
    const float* w_attn = (const float*)d_in[1];
    const float* b_attn = (const float*)d_in[2];
    const float* w_proj = (const float*)d_in[3];
    const float* b_proj = (const float*)d_in[4];
    float* out = (float*)d_out;
    char* base = (char*)d_ws;

    const size_t MB = 1048576;
    float* tbl          = (float*)base;                              // 4 KB
    __hip_bfloat16* Xb  = (__hip_bfloat16*)(base + 4096);            // 8 MB (reused as Yb)
    __hip_bfloat16* Wta = (__hip_bfloat16*)(base + 4096 + 8 * MB);   // 6 MB
    __hip_bfloat16* Wpt = (__hip_bfloat16*)(base + 4096 + 14 * MB);  // 2 MB
    __hip_bfloat16* Qb  = (__hip_bfloat16*)(base + 4096 + 16 * MB);  // 8 MB
    __hip_bfloat16* Kb  = (__hip_bfloat16*)(base + 4096 + 24 * MB);  // 8 MB
    __hip_bfloat16* Vtb = (__hip_bfloat16*)(base + 4096 + 32 * MB);  // 8 MB
    __hip_bfloat16* Yb  = Xb;
    const size_t PART_OFF = 4096 + 40 * MB;
    __hip_bfloat16* Op = (__hip_bfloat16*)(base + PART_OFF);         // 512*8192 bf16 = 8 MB
    float* Mp = (float*)(base + PART_OFF + 8 * MB);
    float* Lp = Mp + (size_t)512 * 128;

    prep_k<<<6145, 256, 0, stream>>>(x, Xb, tbl, w_attn, Wta, w_proj, Wpt);
    qkv_mfma_k<<<dim3(24, 32), 256, 0, stream>>>(Xb, Wta, b_attn, tbl, Qb, Kb, Vtb);
    attn_split_k<<<768, 256, 0, stream>>>(Qb, Kb, Vtb, Yb, Op, Mp, Lp);
    merge_k<<<256, 256, 0, stream>>>(Op, Mp, Lp, Yb);
    proj_mfma_k<<<dim3(16, 32), 256, 0, stream>>>(Yb, Wpt, b_proj, out);
}